// Round 11
// baseline (505.344 us; speedup 1.0000x reference)
//
#include <hip/hip_runtime.h>
#include <hip/hip_bf16.h>
#include <cstdio>

#define N_NODES 100000
#define E_EDGES 3200000
#define N_GRAPH 512
#define HDIM 64
#define BN_EPS 1e-5f
#define NBUCKET ((N_NODES + 255) / 256)   // 391 buckets of 256 nodes
#define NCHUNK 1024                       // edge chunks (16 waves/CU for latency hiding)
#define CHUNK ((E_EDGES + NCHUNK - 1) / NCHUNK) // 3125 edges/chunk
#define SCAP 10240                        // staging ints per bucket (mean 8184 + 22 sigma)
#define CSTRIDE 11008                     // csr region per bucket (SCAP + 768 max node-pads)
#define NPW 8                             // nodes per wave in agg kernels
#define NPL 8                             // nodes per wave in agg_l1
#define WT_STRIDE 68                      // padded LDS stride for transposed W (16B-aligned)

typedef _Float16 f16;
typedef _Float16 half8 __attribute__((ext_vector_type(8)));

// ======== merged radix partition: count + reserve + scatter in ONE kernel ========

__global__ __launch_bounds__(256) void part_k(const int* __restrict__ src,
                                              const int* __restrict__ dst,
                                              int* __restrict__ bcur,
                                              int* __restrict__ staging) {
    __shared__ int h[NBUCKET];
    int c = blockIdx.x, t = threadIdx.x;
    for (int i = t; i < NBUCKET; i += 256) h[i] = 0;
    __syncthreads();
    int e0 = c * CHUNK;
    int e1 = min(e0 + CHUNK, E_EDGES);
    for (int e = e0 + t; e < e1; e += 256)
        atomicAdd(&h[dst[e] >> 8], 1);
    __syncthreads();
    for (int i = t; i < NBUCKET; i += 256)
        h[i] = atomicAdd(&bcur[i], h[i]);        // h[i] becomes global write cursor
    __syncthreads();
    for (int e = e0 + t; e < e1; e += 256) {
        int v = dst[e];                          // L2-hot re-read
        int u = src[e];
        int pos = atomicAdd(&h[v >> 8], 1);      // LDS cursor -> global position
        staging[(v >> 8) * SCAP + pos] = u | ((v & 255) << 17);
    }
}

// tiny: layer-1 affine precompute
__global__ void m1c1_k(const float* __restrict__ w1, const float* __restrict__ b1,
                       const float* __restrict__ bg1, const float* __restrict__ bb1,
                       const float* __restrict__ brm1, const float* __restrict__ brv1,
                       float2* __restrict__ m1c1) {
    int t = threadIdx.x;
    if (t < HDIM) {
        float sc1 = bg1[t] * rsqrtf(brv1[t] + BN_EPS);
        m1c1[t] = make_float2(sc1 * w1[t], (b1[t] - brm1[t]) * sc1 + bb1[t]);
    }
}

// ======== per-bucket CSR build: LDS-staged scatter (verified round-8 version) ====

__global__ __launch_bounds__(256) void bucket_k(const int* __restrict__ staging,
                                                const int* __restrict__ bcur,
                                                const float* __restrict__ x,
                                                int* __restrict__ csr,
                                                int2* __restrict__ ptr2,
                                                float* __restrict__ dinv,
                                                float* __restrict__ xtil) {
    __shared__ int hn[256];
    __shared__ int plp[257];
    __shared__ int ss[256];
    __shared__ int lcnt[256];
    __shared__ int lds_u[CSTRIDE];               // 43KB
    int t = threadIdx.x, b = blockIdx.x;
    int v0 = b << 8;
    int cnt = bcur[b];
    int sb = b * SCAP;
    int pb0 = b * CSTRIDE;
    hn[t] = 0;
    lcnt[t] = 0;
    __syncthreads();
    for (int i = t; i < cnt; i += 256)
        atomicAdd(&hn[staging[sb + i] >> 17], 1);  // degree histogram (LDS atomics)
    __syncthreads();
    int v = v0 + t;
    int deg = hn[t];
    int pd = (deg + 3) & ~3;
    ss[t] = pd;
    __syncthreads();
    for (int off = 1; off < 256; off <<= 1) {
        int add = (t >= off) ? ss[t - off] : 0;
        __syncthreads();
        ss[t] += add;
        __syncthreads();
    }
    plp[t] = ss[t] - pd;
    if (t == 255) plp[256] = ss[255];
    __syncthreads();
    int pcnt = plp[256];                         // mult of 4, <= cnt + 768 <= CSTRIDE
    if (v < N_NODES) {
        float dv = rsqrtf((float)(deg + 1));
        dinv[v] = dv;
        xtil[v] = dv * x[v];
        ptr2[v] = make_int2(pb0 + plp[t], pb0 + plp[t] + pd);
    }
    if (b == NBUCKET - 1 && t == 0) {
        int END = pb0 + pcnt;
        ptr2[N_NODES] = make_int2(END, END);
        ptr2[N_NODES + 1] = make_int2(END, END);
    }
    if (b == 0 && t == 0) xtil[N_NODES] = 0.f;   // gather sentinel
    int4 sent = {N_NODES, N_NODES, N_NODES, N_NODES};
    int lim4 = pcnt >> 2;
    for (int i = t; i < lim4; i += 256) ((int4*)lds_u)[i] = sent;
    __syncthreads();
    for (int i = t; i < cnt; i += 256) {
        int packed = staging[sb + i];            // L2-hot re-read
        int u = packed & 0x1FFFF;
        int vl = packed >> 17;
        int r = atomicAdd(&lcnt[vl], 1);         // LDS atomic rank
        lds_u[plp[vl] + r] = u;
    }
    __syncthreads();
    int4* gout = (int4*)(csr + pb0);
    for (int i = t; i < lim4; i += 256)
        gout[i] = ((int4*)lds_u)[i];             // coalesced 16B copy-out
}

// ======== Layer 1 aggregation: pairs[v] = (dv*sum(xtil[u]) + dv^2*x[v], dv) ====

__global__ __launch_bounds__(256, 8) void agg_l1_k(const int2* __restrict__ ptr2,
                                                   const int* __restrict__ csr,
                                                   const float* __restrict__ dinv,
                                                   const float* __restrict__ xtil,
                                                   const float* __restrict__ x,
                                                   float2* __restrict__ pairs) {
    int tid = threadIdx.x;
    int wave = tid >> 6, lane = tid & 63;
    int h = lane >> 5, l = lane & 31;
    if (blockIdx.x == 0 && tid == 0) pairs[N_NODES] = make_float2(0.f, 0.f);
    int v0 = (blockIdx.x * 4 + wave) * NPL;
    if (v0 >= N_NODES) return;
    for (int n = 0; n < NPL; n += 2) {
        int v = v0 + n + h;
        float s = 0.f;
        int e0 = 0, e1 = 0;
        if (v < N_NODES) { int2 p2 = ptr2[v]; e0 = p2.x; e1 = p2.y; }
        for (int e = e0 + l; e < e1; e += 32)
            s += xtil[csr[e]];             // pad sentinel -> xtil[N]=0
        s += __shfl_xor(s, 1);
        s += __shfl_xor(s, 2);
        s += __shfl_xor(s, 4);
        s += __shfl_xor(s, 8);
        s += __shfl_xor(s, 16);
        if (v < N_NODES && l == 0) {
            float dv = dinv[v];
            pairs[v] = make_float2(dv * s + dv * dv * x[v], dv);
        }
    }
}

// ======== Layer 2: node-pipelined gather overlap + fused @W2 + BN + ReLU ========
// v11: __launch_bounds__(256, 6). Empirical table:
//   (256,4) & (256): VGPR 52, no spill, occ 34%, 89us
//   (256,8):         VGPR 32 + SPILL (64-reg budget too tight), occ 73%, 326us
// (256,6) -> ~85-reg budget: fits the 52-reg pipeline (no spill) while lifting
// the wave cap 4->6 per EU. Tripwires: FETCH ~10.7MB, VGPR<=64.

__global__ __launch_bounds__(256, 6) void agg_l2_k(
    const float2* __restrict__ pairs, const float2* __restrict__ m1c1,
    f16* __restrict__ xout,
    const int2* __restrict__ ptr2, const int* __restrict__ csr,
    const float* __restrict__ W2, const float* __restrict__ bias2,
    const float* __restrict__ bg2, const float* __restrict__ bb2,
    const float* __restrict__ brm2, const float* __restrict__ brv2) {
    __shared__ float wsh_t[HDIM * WT_STRIDE];
    __shared__ float sM[HDIM], sC[HDIM];
    __shared__ float a_lds[4][HDIM];          // per-wave reduced a-vector
    int tid = threadIdx.x;
    for (int i = tid; i < HDIM * HDIM; i += 256)
        wsh_t[(i & 63) * WT_STRIDE + (i >> 6)] = W2[i];    // transpose: [f][k]
    if (tid < HDIM) {
        float sc = bg2[tid] * rsqrtf(brv2[tid] + BN_EPS);
        sM[tid] = sc;
        sC[tid] = (bias2[tid] - brm2[tid]) * sc + bb2[tid];
    }
    __syncthreads();

    int lane = tid & 63;
    int o = lane >> 3, s = lane & 7;
    int f = lane;
    int warp = tid >> 6;
    // sentinel row of xout (read by layer 3)
    if (blockIdx.x == 0 && tid < HDIM) xout[(size_t)N_NODES * HDIM + tid] = (f16)0.f;

    float smf = sM[f], scf = sC[f];
    const float4* wt4 = (const float4*)&wsh_t[f * WT_STRIDE];
    const float4* a4 = (const float4*)a_lds[warp];

    float m1[8], c1[8];
#pragma unroll
    for (int i = 0; i < 8; i++) {
        float2 mc = m1c1[s * 8 + i];
        m1[i] = mc.x; c1[i] = mc.y;
    }

    int v0 = (blockIdx.x * 4 + warp) * NPW;   // grid covers N exactly
    if (v0 >= N_NODES) return;

    // ---- prologue: issue node v0's chunk-0 ----
    int2 p2 = ptr2[v0];
    int e = p2.x, pe1 = p2.y;
    float2 pv = pairs[v0];
    float2 g0, g1, g2, g3;
    {
        int bb = e + o * 4;
        int4 q = *(const int4*)(csr + bb);          // overread stays in csr slack
        bool valid = bb < pe1;
        int u0 = valid ? q.x : N_NODES;
        int u1 = valid ? q.y : N_NODES;
        int u2 = valid ? q.z : N_NODES;
        int u3 = valid ? q.w : N_NODES;
        g0 = pairs[u0]; g1 = pairs[u1]; g2 = pairs[u2]; g3 = pairs[u3];
    }

    for (int n = 0; n < NPW; n++) {
        int v = v0 + n;
        int2 pnxt = ptr2[v + 1];                    // next node (start, padded end)
        float acc[8];
        {
            float cf = (o == 0) ? pv.y : 0.f;       // self-loop, once
#pragma unroll
            for (int i = 0; i < 8; i++)
                acc[i] = cf * fmaxf(m1[i] * pv.x + c1[i], 0.f);
        }
        for (;;) {
            int e2 = e + 32;
            bool last = (e2 >= pe1);                             // wave-uniform
            int nb = last ? pnxt.x : e2;                         // next chunk start
            int nbound = last ? ((n + 1 < NPW) ? pnxt.y : 0) : pe1; // its mask bound
            int bb2 = nb + o * 4;
            int4 q = *(const int4*)(csr + bb2);     // issue next csr quad FIRST
            // consume in-flight gathers (sentinel pairs = (0,0) -> adds 0)
            {
                float2 p = g0;
#pragma unroll
                for (int i = 0; i < 8; i++) acc[i] += p.y * fmaxf(m1[i] * p.x + c1[i], 0.f);
                p = g1;
#pragma unroll
                for (int i = 0; i < 8; i++) acc[i] += p.y * fmaxf(m1[i] * p.x + c1[i], 0.f);
                p = g2;
#pragma unroll
                for (int i = 0; i < 8; i++) acc[i] += p.y * fmaxf(m1[i] * p.x + c1[i], 0.f);
                p = g3;
#pragma unroll
                for (int i = 0; i < 8; i++) acc[i] += p.y * fmaxf(m1[i] * p.x + c1[i], 0.f);
            }
            // issue next chunk's gathers (stay in flight across epilogue on 'last')
            bool valid = bb2 < nbound;
            int u0 = valid ? q.x : N_NODES;
            int u1 = valid ? q.y : N_NODES;
            int u2 = valid ? q.z : N_NODES;
            int u3 = valid ? q.w : N_NODES;
            g0 = pairs[u0]; g1 = pairs[u1]; g2 = pairs[u2]; g3 = pairs[u3];
            if (last) break;
            e = e2;
        }
        e = pnxt.x;                                 // chunk-0 pos of node n+1
        float2 pv_n = pairs[v + 1];                 // prefetch next self (overlaps epilogue)
        // octet reduce: every lane ends with a_k for k = s*8+i
#pragma unroll
        for (int i = 0; i < 8; i++) {
            acc[i] += __shfl_xor(acc[i], 8);
            acc[i] += __shfl_xor(acc[i], 16);
            acc[i] += __shfl_xor(acc[i], 32);
        }
        // LDS transpose: o==0 lanes publish a[64]; all lanes broadcast-read
        if (o == 0) {
            float4* d4 = (float4*)&a_lds[warp][s * 8];
            d4[0] = make_float4(acc[0], acc[1], acc[2], acc[3]);
            d4[1] = make_float4(acc[4], acc[5], acc[6], acc[7]);
        }
        asm volatile("s_waitcnt lgkmcnt(0)" ::: "memory");  // same-wave LDS RAW fence
        float ovp0 = 0.f, ovp1 = 0.f, ovp2 = 0.f, ovp3 = 0.f;
#pragma unroll
        for (int k4 = 0; k4 < 16; k4++) {
            float4 w4 = wt4[k4];
            float4 av = a4[k4];
            ovp0 += av.x * w4.x;
            ovp1 += av.y * w4.y;
            ovp2 += av.z * w4.z;
            ovp3 += av.w * w4.w;
        }
        float ov = (ovp0 + ovp1) + (ovp2 + ovp3);
        float val = fmaxf(pv.y * ov * smf + scf, 0.f);
        xout[(size_t)v * HDIM + f] = (f16)(pv.y * val);    // pre-scaled for layer 3
        pe1 = pnxt.y;
        pv = pv_n;
    }
}

// ======== Layer 3: node-pipelined fp16 row gather + LDS-transpose epilogue ========
// v11: __launch_bounds__(256, 6) — same rationale as agg_l2_k.

__global__ __launch_bounds__(256, 6) void agg_gemm_k(
    const f16* __restrict__ xin, f16* __restrict__ xout,
    const int2* __restrict__ ptr2, const int* __restrict__ csr,
    const float2* __restrict__ pairs,
    const float* __restrict__ W, const float* __restrict__ bias,
    const float* __restrict__ bg, const float* __restrict__ bb,
    const float* __restrict__ brm, const float* __restrict__ brv) {
    __shared__ float wsh_t[HDIM * WT_STRIDE];
    __shared__ float sM[HDIM], sC[HDIM];
    __shared__ float a_lds[4][HDIM];
    int tid = threadIdx.x;
    for (int i = tid; i < HDIM * HDIM; i += 256)
        wsh_t[(i & 63) * WT_STRIDE + (i >> 6)] = W[i];
    if (tid < HDIM) {
        float sc = bg[tid] * rsqrtf(brv[tid] + BN_EPS);
        sM[tid] = sc;
        sC[tid] = (bias[tid] - brm[tid]) * sc + bb[tid];
    }
    __syncthreads();

    int lane = tid & 63;
    int o = lane >> 3, s = lane & 7;
    int f = lane;
    int warp = tid >> 6;
    const half8* __restrict__ xin8 = (const half8*)xin;

    float smf = sM[f], scf = sC[f];
    const float4* wt4 = (const float4*)&wsh_t[f * WT_STRIDE];
    const float4* a4 = (const float4*)a_lds[warp];

    int v0 = (blockIdx.x * 4 + warp) * NPW;
    if (v0 >= N_NODES) return;

    // ---- prologue ----
    int2 p2 = ptr2[v0];
    int e = p2.x, pe1 = p2.y;
    half8 rs = xin8[(size_t)v0 * 8 + s];            // self-loop row
    float dv = pairs[v0].y;
    half8 g0, g1, g2, g3;
    {
        int bb = e + o * 4;
        int4 q = *(const int4*)(csr + bb);
        bool valid = bb < pe1;
        int u0 = valid ? q.x : N_NODES;
        int u1 = valid ? q.y : N_NODES;
        int u2 = valid ? q.z : N_NODES;
        int u3 = valid ? q.w : N_NODES;
        g0 = xin8[(size_t)u0 * 8 + s];
        g1 = xin8[(size_t)u1 * 8 + s];
        g2 = xin8[(size_t)u2 * 8 + s];
        g3 = xin8[(size_t)u3 * 8 + s];
    }

    for (int n = 0; n < NPW; n++) {
        int v = v0 + n;
        int2 pnxt = ptr2[v + 1];
        float acc[8];
        {
            float cf = (o == 0) ? 1.f : 0.f;
#pragma unroll
            for (int i = 0; i < 8; i++) acc[i] = cf * (float)rs[i];
        }
        for (;;) {
            int e2 = e + 32;
            bool last = (e2 >= pe1);
            int nb = last ? pnxt.x : e2;
            int nbound = last ? ((n + 1 < NPW) ? pnxt.y : 0) : pe1;
            int bb2 = nb + o * 4;
            int4 q = *(const int4*)(csr + bb2);     // issue next csr quad FIRST
            // consume in-flight rows via packed-f16 tree (sentinel rows = zeros)
            {
                half8 t01 = g0 + g1;                // 4x v_pk_add_f16 each
                half8 t23 = g2 + g3;
                half8 tt = t01 + t23;
#pragma unroll
                for (int i = 0; i < 8; i++) acc[i] += (float)tt[i];
            }
            bool valid = bb2 < nbound;
            int u0 = valid ? q.x : N_NODES;
            int u1 = valid ? q.y : N_NODES;
            int u2 = valid ? q.z : N_NODES;
            int u3 = valid ? q.w : N_NODES;
            g0 = xin8[(size_t)u0 * 8 + s];
            g1 = xin8[(size_t)u1 * 8 + s];
            g2 = xin8[(size_t)u2 * 8 + s];
            g3 = xin8[(size_t)u3 * 8 + s];
            if (last) break;
            e = e2;
        }
        e = pnxt.x;
        half8 rs_n = xin8[(size_t)(v + 1) * 8 + s]; // prefetch next self row
        float dv_n = pairs[v + 1].y;
        // octet reduce
#pragma unroll
        for (int i = 0; i < 8; i++) {
            acc[i] += __shfl_xor(acc[i], 8);
            acc[i] += __shfl_xor(acc[i], 16);
            acc[i] += __shfl_xor(acc[i], 32);
        }
        // LDS transpose epilogue
        if (o == 0) {
            float4* d4 = (float4*)&a_lds[warp][s * 8];
            d4[0] = make_float4(acc[0], acc[1], acc[2], acc[3]);
            d4[1] = make_float4(acc[4], acc[5], acc[6], acc[7]);
        }
        asm volatile("s_waitcnt lgkmcnt(0)" ::: "memory");
        float ovp0 = 0.f, ovp1 = 0.f, ovp2 = 0.f, ovp3 = 0.f;
#pragma unroll
        for (int k4 = 0; k4 < 16; k4++) {
            float4 w4 = wt4[k4];
            float4 av = a4[k4];
            ovp0 += av.x * w4.x;
            ovp1 += av.y * w4.y;
            ovp2 += av.z * w4.z;
            ovp3 += av.w * w4.w;
        }
        float ov = (ovp0 + ovp1) + (ovp2 + ovp3);
        float val = fmaxf(dv * ov * smf + scf, 0.f);
        xout[(size_t)v * HDIM + f] = (f16)val;
        pe1 = pnxt.y;
        rs = rs_n;
        dv = dv_n;
    }
}

// ======== Pool (mean/max per graph) + MLP head ========

__device__ inline int lower_bound_i(const int* __restrict__ a, int n, int val) {
    int lo = 0, hi = n;
    while (lo < hi) {
        int mid = (lo + hi) >> 1;
        if (a[mid] < val) lo = mid + 1; else hi = mid;
    }
    return lo;
}

__global__ void pool_mlp_k(const f16* __restrict__ x, const int* __restrict__ batch,
                           const float* __restrict__ wl1, const float* __restrict__ bl1,
                           const float* __restrict__ wl2, const float* __restrict__ bl2,
                           const float* __restrict__ bg, const float* __restrict__ bb,
                           const float* __restrict__ brm, const float* __restrict__ brv,
                           float* __restrict__ out) {
    int g = blockIdx.x;
    int tid = threadIdx.x;
    int w = tid >> 6;
    int f = tid & 63;
    int start = lower_bound_i(batch, N_NODES, g);
    int end = lower_bound_i(batch, N_NODES, g + 1);
    float sum = 0.f;
    float mx = -3.402823466e38f;
#pragma unroll 2
    for (int v = start + w; v < end; v += 4) {
        float val = (float)x[(size_t)v * HDIM + f];
        sum += val;
        mx = fmaxf(mx, val);
    }
    __shared__ float ssum[4][HDIM], smax[4][HDIM];
    __shared__ float zs[2 * HDIM];
    ssum[w][f] = sum;
    smax[w][f] = mx;
    __syncthreads();
    if (tid < 64) {
        float sm = ssum[0][f] + ssum[1][f] + ssum[2][f] + ssum[3][f];
        float m = fmaxf(fmaxf(smax[0][f], smax[1][f]), fmaxf(smax[2][f], smax[3][f]));
        float cnt = (float)(end - start);
        zs[f] = sm / fmaxf(cnt, 1.f);
        zs[HDIM + f] = m;
    }
    __syncthreads();
    if (tid >= 64) return;

    float o = bl1[f];
#pragma unroll 8
    for (int k = 0; k < 2 * HDIM; k++) {
        o += zs[k] * wl1[k * HDIM + f];
    }
    float sc = bg[f] * rsqrtf(brv[f] + BN_EPS);
    o = fmaxf((o - brm[f]) * sc + bb[f], 0.f);

    float p0 = o * wl2[f * 2 + 0];
    float p1 = o * wl2[f * 2 + 1];
    for (int off = 32; off > 0; off >>= 1) {
        p0 += __shfl_down(p0, off);
        p1 += __shfl_down(p1, off);
    }
    if (f == 0) {
        out[g * 2 + 0] = p0 + bl2[0];
        out[g * 2 + 1] = p1 + bl2[1];
    }
}

// ======== launch ========

extern "C" void kernel_launch(void* const* d_in, const int* in_sizes, int n_in,
                              void* d_out, int out_size, void* d_ws, size_t ws_size,
                              hipStream_t stream) {
    const float* x    = (const float*)d_in[0];
    const int* src    = (const int*)d_in[1];
    const int* dst    = (const int*)d_in[2];
    const int* batch  = (const int*)d_in[3];
    const float* w1   = (const float*)d_in[4];
    const float* b1   = (const float*)d_in[5];
    const float* w2   = (const float*)d_in[6];
    const float* b2   = (const float*)d_in[7];
    const float* w3   = (const float*)d_in[8];
    const float* b3   = (const float*)d_in[9];
    const float* wl1  = (const float*)d_in[10];
    const float* bl1  = (const float*)d_in[11];
    const float* wl2  = (const float*)d_in[12];
    const float* bl2  = (const float*)d_in[13];
    const float* bn1g = (const float*)d_in[14];
    const float* bn1b = (const float*)d_in[15];
    const float* bn1rm = (const float*)d_in[16];
    const float* bn1rv = (const float*)d_in[17];
    const float* bn2g = (const float*)d_in[18];
    const float* bn2b = (const float*)d_in[19];
    const float* bn2rm = (const float*)d_in[20];
    const float* bn2rv = (const float*)d_in[21];
    const float* bn3g = (const float*)d_in[22];
    const float* bn3b = (const float*)d_in[23];
    const float* bn3rm = (const float*)d_in[24];
    const float* bn3rv = (const float*)d_in[25];
    const float* bnlg = (const float*)d_in[26];
    const float* bnlb = (const float*)d_in[27];
    const float* bnlrm = (const float*)d_in[28];
    const float* bnlrv = (const float*)d_in[29];
    float* out = (float*)d_out;

    char* ws = (char*)d_ws;
    size_t off = 0;
    auto alloc = [&](size_t bytes) -> char* {
        off = (off + 255) & ~(size_t)255;
        char* p = ws + off;
        off += bytes;
        return p;
    };
    int*    bcur     = (int*)alloc((size_t)NBUCKET * 4);
    int*    staging  = (int*)alloc((size_t)NBUCKET * SCAP * 4);       // 16.0MB
    int*    csr      = (int*)alloc(((size_t)NBUCKET * CSTRIDE + 64) * 4); // 17.2MB
    int2*   ptr2     = (int2*)alloc(((size_t)N_NODES + 2) * 8);
    float*  dinv     = (float*)alloc((size_t)N_NODES * 4);
    float*  xtil     = (float*)alloc(((size_t)N_NODES + 1) * 4);
    float2* pairs    = (float2*)alloc(((size_t)N_NODES + 1) * 8);
    float2* m1c1     = (float2*)alloc((size_t)HDIM * 8);
    f16*    x2       = (f16*)alloc(((size_t)N_NODES + 1) * HDIM * 2);
    f16*    x3       = (f16*)staging;             // alias: staging dead after bucket_k
    if (off > ws_size) {
        fprintf(stderr, "kernel_launch: ws too small (%zu > %zu)\n", off, ws_size);
    }

    const int NB_AGG = (N_NODES + 4 * NPW - 1) / (4 * NPW);  // 3125

    hipMemsetAsync(bcur, 0, (size_t)NBUCKET * 4, stream);
    part_k<<<NCHUNK, 256, 0, stream>>>(src, dst, bcur, staging);
    m1c1_k<<<1, 64, 0, stream>>>(w1, b1, bn1g, bn1b, bn1rm, bn1rv, m1c1);
    bucket_k<<<NBUCKET, 256, 0, stream>>>(staging, bcur, x, csr, ptr2, dinv, xtil);
    agg_l1_k<<<NB_AGG, 256, 0, stream>>>(ptr2, csr, dinv, xtil, x, pairs);

    agg_l2_k<<<NB_AGG, 256, 0, stream>>>(pairs, m1c1, x2, ptr2, csr,
                                         w2, b2, bn2g, bn2b, bn2rm, bn2rv);
    agg_gemm_k<<<NB_AGG, 256, 0, stream>>>(x2, x3, ptr2, csr, pairs,
                                           w3, b3, bn3g, bn3b, bn3rm, bn3rv);

    pool_mlp_k<<<N_GRAPH, 256, 0, stream>>>(x3, batch, wl1, bl1, wl2, bl2,
                                            bnlg, bnlb, bnlrm, bnlrv, out);
}

// Round 13
// 398.061 us; speedup vs baseline: 1.2695x; 1.2695x over previous
//
#include <hip/hip_runtime.h>
#include <hip/hip_bf16.h>
#include <cstdio>

#define N_NODES 100000
#define E_EDGES 3200000
#define N_GRAPH 512
#define HDIM 64
#define BN_EPS 1e-5f
#define NBUCKET ((N_NODES + 255) / 256)   // 391 buckets of 256 nodes
#define NCHUNK 1024                       // edge chunks (16 waves/CU for latency hiding)
#define CHUNK ((E_EDGES + NCHUNK - 1) / NCHUNK) // 3125 edges/chunk
#define SCAP 10240                        // staging ints per bucket (mean 8184 + 22 sigma)
#define CSTRIDE 11008                     // csr region per bucket (SCAP + 768 max node-pads)
#define NPW 8                             // nodes per wave in agg kernels
#define NPL 8                             // nodes per wave in agg_l1
#define WT_STRIDE 68                      // padded LDS stride for transposed W (16B-aligned)

typedef _Float16 f16;
typedef _Float16 half8 __attribute__((ext_vector_type(8)));

// ======== merged radix partition: count + reserve + scatter in ONE kernel ========

__global__ __launch_bounds__(256) void part_k(const int* __restrict__ src,
                                              const int* __restrict__ dst,
                                              int* __restrict__ bcur,
                                              int* __restrict__ staging) {
    __shared__ int h[NBUCKET];
    int c = blockIdx.x, t = threadIdx.x;
    for (int i = t; i < NBUCKET; i += 256) h[i] = 0;
    __syncthreads();
    int e0 = c * CHUNK;
    int e1 = min(e0 + CHUNK, E_EDGES);
    for (int e = e0 + t; e < e1; e += 256)
        atomicAdd(&h[dst[e] >> 8], 1);
    __syncthreads();
    for (int i = t; i < NBUCKET; i += 256)
        h[i] = atomicAdd(&bcur[i], h[i]);        // h[i] becomes global write cursor
    __syncthreads();
    for (int e = e0 + t; e < e1; e += 256) {
        int v = dst[e];                          // L2-hot re-read
        int u = src[e];
        int pos = atomicAdd(&h[v >> 8], 1);      // LDS cursor -> global position
        staging[(v >> 8) * SCAP + pos] = u | ((v & 255) << 17);
    }
}

// tiny: layer-1 affine precompute
__global__ void m1c1_k(const float* __restrict__ w1, const float* __restrict__ b1,
                       const float* __restrict__ bg1, const float* __restrict__ bb1,
                       const float* __restrict__ brm1, const float* __restrict__ brv1,
                       float2* __restrict__ m1c1) {
    int t = threadIdx.x;
    if (t < HDIM) {
        float sc1 = bg1[t] * rsqrtf(brv1[t] + BN_EPS);
        m1c1[t] = make_float2(sc1 * w1[t], (b1[t] - brm1[t]) * sc1 + bb1[t]);
    }
}

// ======== per-bucket CSR build: LDS-staged scatter (verified round-8 version) ====
// Direct 4B global rank-scatter regressed ~20us (64 lanes -> 64 distinct 32B
// sectors per wave-inst, store-issue bound). LDS staging + coalesced int4
// copy-out is the measured winner.

__global__ __launch_bounds__(256) void bucket_k(const int* __restrict__ staging,
                                                const int* __restrict__ bcur,
                                                const float* __restrict__ x,
                                                int* __restrict__ csr,
                                                int2* __restrict__ ptr2,
                                                float* __restrict__ dinv,
                                                float* __restrict__ xtil) {
    __shared__ int hn[256];
    __shared__ int plp[257];
    __shared__ int ss[256];
    __shared__ int lcnt[256];
    __shared__ int lds_u[CSTRIDE];               // 43KB
    int t = threadIdx.x, b = blockIdx.x;
    int v0 = b << 8;
    int cnt = bcur[b];
    int sb = b * SCAP;
    int pb0 = b * CSTRIDE;
    hn[t] = 0;
    lcnt[t] = 0;
    __syncthreads();
    for (int i = t; i < cnt; i += 256)
        atomicAdd(&hn[staging[sb + i] >> 17], 1);  // degree histogram (LDS atomics)
    __syncthreads();
    int v = v0 + t;
    int deg = hn[t];
    int pd = (deg + 3) & ~3;
    ss[t] = pd;
    __syncthreads();
    for (int off = 1; off < 256; off <<= 1) {
        int add = (t >= off) ? ss[t - off] : 0;
        __syncthreads();
        ss[t] += add;
        __syncthreads();
    }
    plp[t] = ss[t] - pd;
    if (t == 255) plp[256] = ss[255];
    __syncthreads();
    int pcnt = plp[256];                         // mult of 4, <= cnt + 768 <= CSTRIDE
    if (v < N_NODES) {
        float dv = rsqrtf((float)(deg + 1));
        dinv[v] = dv;
        xtil[v] = dv * x[v];
        ptr2[v] = make_int2(pb0 + plp[t], pb0 + plp[t] + pd);
    }
    if (b == NBUCKET - 1 && t == 0) {
        int END = pb0 + pcnt;
        ptr2[N_NODES] = make_int2(END, END);
        ptr2[N_NODES + 1] = make_int2(END, END);
    }
    if (b == 0 && t == 0) xtil[N_NODES] = 0.f;   // gather sentinel
    int4 sent = {N_NODES, N_NODES, N_NODES, N_NODES};
    int lim4 = pcnt >> 2;
    for (int i = t; i < lim4; i += 256) ((int4*)lds_u)[i] = sent;
    __syncthreads();
    for (int i = t; i < cnt; i += 256) {
        int packed = staging[sb + i];            // L2-hot re-read
        int u = packed & 0x1FFFF;
        int vl = packed >> 17;
        int r = atomicAdd(&lcnt[vl], 1);         // LDS atomic rank
        lds_u[plp[vl] + r] = u;
    }
    __syncthreads();
    int4* gout = (int4*)(csr + pb0);
    for (int i = t; i < lim4; i += 256)
        gout[i] = ((int4*)lds_u)[i];             // coalesced 16B copy-out
}

// ======== Layer 1 aggregation: pairs[v] = (dv*sum(xtil[u]) + dv^2*x[v], dv) ====

__global__ __launch_bounds__(256, 8) void agg_l1_k(const int2* __restrict__ ptr2,
                                                   const int* __restrict__ csr,
                                                   const float* __restrict__ dinv,
                                                   const float* __restrict__ xtil,
                                                   const float* __restrict__ x,
                                                   float2* __restrict__ pairs) {
    int tid = threadIdx.x;
    int wave = tid >> 6, lane = tid & 63;
    int h = lane >> 5, l = lane & 31;
    if (blockIdx.x == 0 && tid == 0) pairs[N_NODES] = make_float2(0.f, 0.f);
    int v0 = (blockIdx.x * 4 + wave) * NPL;
    if (v0 >= N_NODES) return;
    for (int n = 0; n < NPL; n += 2) {
        int v = v0 + n + h;
        float s = 0.f;
        int e0 = 0, e1 = 0;
        if (v < N_NODES) { int2 p2 = ptr2[v]; e0 = p2.x; e1 = p2.y; }
        for (int e = e0 + l; e < e1; e += 32)
            s += xtil[csr[e]];             // pad sentinel -> xtil[N]=0
        s += __shfl_xor(s, 1);
        s += __shfl_xor(s, 2);
        s += __shfl_xor(s, 4);
        s += __shfl_xor(s, 8);
        s += __shfl_xor(s, 16);
        if (v < N_NODES && l == 0) {
            float dv = dinv[v];
            pairs[v] = make_float2(dv * s + dv * dv * x[v], dv);
        }
    }
}

// ======== Layer 2: node-pipelined gather overlap + fused @W2 + BN + ReLU ========
// launch_bounds (256,4): the FULL sweep is measured — (256,4)/(256): VGPR 52,
// no spill, 89us. (256,6): VGPR 40 + spill, 147us. (256,8): VGPR 32 + spill,
// 326us. Declared min-waves > 4 makes the allocator shrink VGPR below the
// pipeline's ~52-reg need and spill in-loop. (256,4) is the optimum.

__global__ __launch_bounds__(256, 4) void agg_l2_k(
    const float2* __restrict__ pairs, const float2* __restrict__ m1c1,
    f16* __restrict__ xout,
    const int2* __restrict__ ptr2, const int* __restrict__ csr,
    const float* __restrict__ W2, const float* __restrict__ bias2,
    const float* __restrict__ bg2, const float* __restrict__ bb2,
    const float* __restrict__ brm2, const float* __restrict__ brv2) {
    __shared__ float wsh_t[HDIM * WT_STRIDE];
    __shared__ float sM[HDIM], sC[HDIM];
    __shared__ float a_lds[4][HDIM];          // per-wave reduced a-vector
    int tid = threadIdx.x;
    for (int i = tid; i < HDIM * HDIM; i += 256)
        wsh_t[(i & 63) * WT_STRIDE + (i >> 6)] = W2[i];    // transpose: [f][k]
    if (tid < HDIM) {
        float sc = bg2[tid] * rsqrtf(brv2[tid] + BN_EPS);
        sM[tid] = sc;
        sC[tid] = (bias2[tid] - brm2[tid]) * sc + bb2[tid];
    }
    __syncthreads();

    int lane = tid & 63;
    int o = lane >> 3, s = lane & 7;
    int f = lane;
    int warp = tid >> 6;
    // sentinel row of xout (read by layer 3)
    if (blockIdx.x == 0 && tid < HDIM) xout[(size_t)N_NODES * HDIM + tid] = (f16)0.f;

    float smf = sM[f], scf = sC[f];
    const float4* wt4 = (const float4*)&wsh_t[f * WT_STRIDE];
    const float4* a4 = (const float4*)a_lds[warp];

    float m1[8], c1[8];
#pragma unroll
    for (int i = 0; i < 8; i++) {
        float2 mc = m1c1[s * 8 + i];
        m1[i] = mc.x; c1[i] = mc.y;
    }

    int v0 = (blockIdx.x * 4 + warp) * NPW;   // grid covers N exactly
    if (v0 >= N_NODES) return;

    // ---- prologue: issue node v0's chunk-0 ----
    int2 p2 = ptr2[v0];
    int e = p2.x, pe1 = p2.y;
    float2 pv = pairs[v0];
    float2 g0, g1, g2, g3;
    {
        int bb = e + o * 4;
        int4 q = *(const int4*)(csr + bb);          // overread stays in csr slack
        bool valid = bb < pe1;
        int u0 = valid ? q.x : N_NODES;
        int u1 = valid ? q.y : N_NODES;
        int u2 = valid ? q.z : N_NODES;
        int u3 = valid ? q.w : N_NODES;
        g0 = pairs[u0]; g1 = pairs[u1]; g2 = pairs[u2]; g3 = pairs[u3];
    }

    for (int n = 0; n < NPW; n++) {
        int v = v0 + n;
        int2 pnxt = ptr2[v + 1];                    // next node (start, padded end)
        float acc[8];
        {
            float cf = (o == 0) ? pv.y : 0.f;       // self-loop, once
#pragma unroll
            for (int i = 0; i < 8; i++)
                acc[i] = cf * fmaxf(m1[i] * pv.x + c1[i], 0.f);
        }
        for (;;) {
            int e2 = e + 32;
            bool last = (e2 >= pe1);                             // wave-uniform
            int nb = last ? pnxt.x : e2;                         // next chunk start
            int nbound = last ? ((n + 1 < NPW) ? pnxt.y : 0) : pe1; // its mask bound
            int bb2 = nb + o * 4;
            int4 q = *(const int4*)(csr + bb2);     // issue next csr quad FIRST
            // consume in-flight gathers (sentinel pairs = (0,0) -> adds 0)
            {
                float2 p = g0;
#pragma unroll
                for (int i = 0; i < 8; i++) acc[i] += p.y * fmaxf(m1[i] * p.x + c1[i], 0.f);
                p = g1;
#pragma unroll
                for (int i = 0; i < 8; i++) acc[i] += p.y * fmaxf(m1[i] * p.x + c1[i], 0.f);
                p = g2;
#pragma unroll
                for (int i = 0; i < 8; i++) acc[i] += p.y * fmaxf(m1[i] * p.x + c1[i], 0.f);
                p = g3;
#pragma unroll
                for (int i = 0; i < 8; i++) acc[i] += p.y * fmaxf(m1[i] * p.x + c1[i], 0.f);
            }
            // issue next chunk's gathers (stay in flight across epilogue on 'last')
            bool valid = bb2 < nbound;
            int u0 = valid ? q.x : N_NODES;
            int u1 = valid ? q.y : N_NODES;
            int u2 = valid ? q.z : N_NODES;
            int u3 = valid ? q.w : N_NODES;
            g0 = pairs[u0]; g1 = pairs[u1]; g2 = pairs[u2]; g3 = pairs[u3];
            if (last) break;
            e = e2;
        }
        e = pnxt.x;                                 // chunk-0 pos of node n+1
        float2 pv_n = pairs[v + 1];                 // prefetch next self (overlaps epilogue)
        // octet reduce: every lane ends with a_k for k = s*8+i
#pragma unroll
        for (int i = 0; i < 8; i++) {
            acc[i] += __shfl_xor(acc[i], 8);
            acc[i] += __shfl_xor(acc[i], 16);
            acc[i] += __shfl_xor(acc[i], 32);
        }
        // LDS transpose: o==0 lanes publish a[64]; all lanes broadcast-read
        if (o == 0) {
            float4* d4 = (float4*)&a_lds[warp][s * 8];
            d4[0] = make_float4(acc[0], acc[1], acc[2], acc[3]);
            d4[1] = make_float4(acc[4], acc[5], acc[6], acc[7]);
        }
        asm volatile("s_waitcnt lgkmcnt(0)" ::: "memory");  // same-wave LDS RAW fence
        float ovp0 = 0.f, ovp1 = 0.f, ovp2 = 0.f, ovp3 = 0.f;
#pragma unroll
        for (int k4 = 0; k4 < 16; k4++) {
            float4 w4 = wt4[k4];
            float4 av = a4[k4];
            ovp0 += av.x * w4.x;
            ovp1 += av.y * w4.y;
            ovp2 += av.z * w4.z;
            ovp3 += av.w * w4.w;
        }
        float ov = (ovp0 + ovp1) + (ovp2 + ovp3);
        float val = fmaxf(pv.y * ov * smf + scf, 0.f);
        xout[(size_t)v * HDIM + f] = (f16)(pv.y * val);    // pre-scaled for layer 3
        pe1 = pnxt.y;
        pv = pv_n;
    }
}

// ======== Layer 3: node-pipelined fp16 row gather + LDS-transpose epilogue ========
// consume uses packed-f16 pairwise tree (12x v_pk_add_f16) + 8 cvt+add —
// verified win; absmax unchanged at the f16 quantization floor.

__global__ __launch_bounds__(256, 4) void agg_gemm_k(
    const f16* __restrict__ xin, f16* __restrict__ xout,
    const int2* __restrict__ ptr2, const int* __restrict__ csr,
    const float2* __restrict__ pairs,
    const float* __restrict__ W, const float* __restrict__ bias,
    const float* __restrict__ bg, const float* __restrict__ bb,
    const float* __restrict__ brm, const float* __restrict__ brv) {
    __shared__ float wsh_t[HDIM * WT_STRIDE];
    __shared__ float sM[HDIM], sC[HDIM];
    __shared__ float a_lds[4][HDIM];
    int tid = threadIdx.x;
    for (int i = tid; i < HDIM * HDIM; i += 256)
        wsh_t[(i & 63) * WT_STRIDE + (i >> 6)] = W[i];
    if (tid < HDIM) {
        float sc = bg[tid] * rsqrtf(brv[tid] + BN_EPS);
        sM[tid] = sc;
        sC[tid] = (bias[tid] - brm[tid]) * sc + bb[tid];
    }
    __syncthreads();

    int lane = tid & 63;
    int o = lane >> 3, s = lane & 7;
    int f = lane;
    int warp = tid >> 6;
    const half8* __restrict__ xin8 = (const half8*)xin;

    float smf = sM[f], scf = sC[f];
    const float4* wt4 = (const float4*)&wsh_t[f * WT_STRIDE];
    const float4* a4 = (const float4*)a_lds[warp];

    int v0 = (blockIdx.x * 4 + warp) * NPW;
    if (v0 >= N_NODES) return;

    // ---- prologue ----
    int2 p2 = ptr2[v0];
    int e = p2.x, pe1 = p2.y;
    half8 rs = xin8[(size_t)v0 * 8 + s];            // self-loop row
    float dv = pairs[v0].y;
    half8 g0, g1, g2, g3;
    {
        int bb = e + o * 4;
        int4 q = *(const int4*)(csr + bb);
        bool valid = bb < pe1;
        int u0 = valid ? q.x : N_NODES;
        int u1 = valid ? q.y : N_NODES;
        int u2 = valid ? q.z : N_NODES;
        int u3 = valid ? q.w : N_NODES;
        g0 = xin8[(size_t)u0 * 8 + s];
        g1 = xin8[(size_t)u1 * 8 + s];
        g2 = xin8[(size_t)u2 * 8 + s];
        g3 = xin8[(size_t)u3 * 8 + s];
    }

    for (int n = 0; n < NPW; n++) {
        int v = v0 + n;
        int2 pnxt = ptr2[v + 1];
        float acc[8];
        {
            float cf = (o == 0) ? 1.f : 0.f;
#pragma unroll
            for (int i = 0; i < 8; i++) acc[i] = cf * (float)rs[i];
        }
        for (;;) {
            int e2 = e + 32;
            bool last = (e2 >= pe1);
            int nb = last ? pnxt.x : e2;
            int nbound = last ? ((n + 1 < NPW) ? pnxt.y : 0) : pe1;
            int bb2 = nb + o * 4;
            int4 q = *(const int4*)(csr + bb2);     // issue next csr quad FIRST
            // consume in-flight rows via packed-f16 tree (sentinel rows = zeros)
            {
                half8 t01 = g0 + g1;                // 4x v_pk_add_f16 each
                half8 t23 = g2 + g3;
                half8 tt = t01 + t23;
#pragma unroll
                for (int i = 0; i < 8; i++) acc[i] += (float)tt[i];
            }
            bool valid = bb2 < nbound;
            int u0 = valid ? q.x : N_NODES;
            int u1 = valid ? q.y : N_NODES;
            int u2 = valid ? q.z : N_NODES;
            int u3 = valid ? q.w : N_NODES;
            g0 = xin8[(size_t)u0 * 8 + s];
            g1 = xin8[(size_t)u1 * 8 + s];
            g2 = xin8[(size_t)u2 * 8 + s];
            g3 = xin8[(size_t)u3 * 8 + s];
            if (last) break;
            e = e2;
        }
        e = pnxt.x;
        half8 rs_n = xin8[(size_t)(v + 1) * 8 + s]; // prefetch next self row
        float dv_n = pairs[v + 1].y;
        // octet reduce
#pragma unroll
        for (int i = 0; i < 8; i++) {
            acc[i] += __shfl_xor(acc[i], 8);
            acc[i] += __shfl_xor(acc[i], 16);
            acc[i] += __shfl_xor(acc[i], 32);
        }
        // LDS transpose epilogue
        if (o == 0) {
            float4* d4 = (float4*)&a_lds[warp][s * 8];
            d4[0] = make_float4(acc[0], acc[1], acc[2], acc[3]);
            d4[1] = make_float4(acc[4], acc[5], acc[6], acc[7]);
        }
        asm volatile("s_waitcnt lgkmcnt(0)" ::: "memory");
        float ovp0 = 0.f, ovp1 = 0.f, ovp2 = 0.f, ovp3 = 0.f;
#pragma unroll
        for (int k4 = 0; k4 < 16; k4++) {
            float4 w4 = wt4[k4];
            float4 av = a4[k4];
            ovp0 += av.x * w4.x;
            ovp1 += av.y * w4.y;
            ovp2 += av.z * w4.z;
            ovp3 += av.w * w4.w;
        }
        float ov = (ovp0 + ovp1) + (ovp2 + ovp3);
        float val = fmaxf(dv * ov * smf + scf, 0.f);
        xout[(size_t)v * HDIM + f] = (f16)val;
        pe1 = pnxt.y;
        rs = rs_n;
        dv = dv_n;
    }
}

// ======== Pool (mean/max per graph) + MLP head ========

__device__ inline int lower_bound_i(const int* __restrict__ a, int n, int val) {
    int lo = 0, hi = n;
    while (lo < hi) {
        int mid = (lo + hi) >> 1;
        if (a[mid] < val) lo = mid + 1; else hi = mid;
    }
    return lo;
}

__global__ void pool_mlp_k(const f16* __restrict__ x, const int* __restrict__ batch,
                           const float* __restrict__ wl1, const float* __restrict__ bl1,
                           const float* __restrict__ wl2, const float* __restrict__ bl2,
                           const float* __restrict__ bg, const float* __restrict__ bb,
                           const float* __restrict__ brm, const float* __restrict__ brv,
                           float* __restrict__ out) {
    int g = blockIdx.x;
    int tid = threadIdx.x;
    int w = tid >> 6;
    int f = tid & 63;
    int start = lower_bound_i(batch, N_NODES, g);
    int end = lower_bound_i(batch, N_NODES, g + 1);
    float sum = 0.f;
    float mx = -3.402823466e38f;
#pragma unroll 2
    for (int v = start + w; v < end; v += 4) {
        float val = (float)x[(size_t)v * HDIM + f];
        sum += val;
        mx = fmaxf(mx, val);
    }
    __shared__ float ssum[4][HDIM], smax[4][HDIM];
    __shared__ float zs[2 * HDIM];
    ssum[w][f] = sum;
    smax[w][f] = mx;
    __syncthreads();
    if (tid < 64) {
        float sm = ssum[0][f] + ssum[1][f] + ssum[2][f] + ssum[3][f];
        float m = fmaxf(fmaxf(smax[0][f], smax[1][f]), fmaxf(smax[2][f], smax[3][f]));
        float cnt = (float)(end - start);
        zs[f] = sm / fmaxf(cnt, 1.f);
        zs[HDIM + f] = m;
    }
    __syncthreads();
    if (tid >= 64) return;

    float o = bl1[f];
#pragma unroll 8
    for (int k = 0; k < 2 * HDIM; k++) {
        o += zs[k] * wl1[k * HDIM + f];
    }
    float sc = bg[f] * rsqrtf(brv[f] + BN_EPS);
    o = fmaxf((o - brm[f]) * sc + bb[f], 0.f);

    float p0 = o * wl2[f * 2 + 0];
    float p1 = o * wl2[f * 2 + 1];
    for (int off = 32; off > 0; off >>= 1) {
        p0 += __shfl_down(p0, off);
        p1 += __shfl_down(p1, off);
    }
    if (f == 0) {
        out[g * 2 + 0] = p0 + bl2[0];
        out[g * 2 + 1] = p1 + bl2[1];
    }
}

// ======== launch ========

extern "C" void kernel_launch(void* const* d_in, const int* in_sizes, int n_in,
                              void* d_out, int out_size, void* d_ws, size_t ws_size,
                              hipStream_t stream) {
    const float* x    = (const float*)d_in[0];
    const int* src    = (const int*)d_in[1];
    const int* dst    = (const int*)d_in[2];
    const int* batch  = (const int*)d_in[3];
    const float* w1   = (const float*)d_in[4];
    const float* b1   = (const float*)d_in[5];
    const float* w2   = (const float*)d_in[6];
    const float* b2   = (const float*)d_in[7];
    const float* w3   = (const float*)d_in[8];
    const float* b3   = (const float*)d_in[9];
    const float* wl1  = (const float*)d_in[10];
    const float* bl1  = (const float*)d_in[11];
    const float* wl2  = (const float*)d_in[12];
    const float* bl2  = (const float*)d_in[13];
    const float* bn1g = (const float*)d_in[14];
    const float* bn1b = (const float*)d_in[15];
    const float* bn1rm = (const float*)d_in[16];
    const float* bn1rv = (const float*)d_in[17];
    const float* bn2g = (const float*)d_in[18];
    const float* bn2b = (const float*)d_in[19];
    const float* bn2rm = (const float*)d_in[20];
    const float* bn2rv = (const float*)d_in[21];
    const float* bn3g = (const float*)d_in[22];
    const float* bn3b = (const float*)d_in[23];
    const float* bn3rm = (const float*)d_in[24];
    const float* bn3rv = (const float*)d_in[25];
    const float* bnlg = (const float*)d_in[26];
    const float* bnlb = (const float*)d_in[27];
    const float* bnlrm = (const float*)d_in[28];
    const float* bnlrv = (const float*)d_in[29];
    float* out = (float*)d_out;

    char* ws = (char*)d_ws;
    size_t off = 0;
    auto alloc = [&](size_t bytes) -> char* {
        off = (off + 255) & ~(size_t)255;
        char* p = ws + off;
        off += bytes;
        return p;
    };
    int*    bcur     = (int*)alloc((size_t)NBUCKET * 4);
    int*    staging  = (int*)alloc((size_t)NBUCKET * SCAP * 4);       // 16.0MB
    int*    csr      = (int*)alloc(((size_t)NBUCKET * CSTRIDE + 64) * 4); // 17.2MB
    int2*   ptr2     = (int2*)alloc(((size_t)N_NODES + 2) * 8);
    float*  dinv     = (float*)alloc((size_t)N_NODES * 4);
    float*  xtil     = (float*)alloc(((size_t)N_NODES + 1) * 4);
    float2* pairs    = (float2*)alloc(((size_t)N_NODES + 1) * 8);
    float2* m1c1     = (float2*)alloc((size_t)HDIM * 8);
    f16*    x2       = (f16*)alloc(((size_t)N_NODES + 1) * HDIM * 2);
    f16*    x3       = (f16*)staging;             // alias: staging dead after bucket_k
    if (off > ws_size) {
        fprintf(stderr, "kernel_launch: ws too small (%zu > %zu)\n", off, ws_size);
    }

    const int NB_AGG = (N_NODES + 4 * NPW - 1) / (4 * NPW);  // 3125

    hipMemsetAsync(bcur, 0, (size_t)NBUCKET * 4, stream);
    part_k<<<NCHUNK, 256, 0, stream>>>(src, dst, bcur, staging);
    m1c1_k<<<1, 64, 0, stream>>>(w1, b1, bn1g, bn1b, bn1rm, bn1rv, m1c1);
    bucket_k<<<NBUCKET, 256, 0, stream>>>(staging, bcur, x, csr, ptr2, dinv, xtil);
    agg_l1_k<<<NB_AGG, 256, 0, stream>>>(ptr2, csr, dinv, xtil, x, pairs);

    agg_l2_k<<<NB_AGG, 256, 0, stream>>>(pairs, m1c1, x2, ptr2, csr,
                                         w2, b2, bn2g, bn2b, bn2rm, bn2rv);
    agg_gemm_k<<<NB_AGG, 256, 0, stream>>>(x2, x3, ptr2, csr, pairs,
                                           w3, b3, bn3g, bn3b, bn3rm, bn3rv);

    pool_mlp_k<<<N_GRAPH, 256, 0, stream>>>(x3, batch, wl1, bl1, wl2, bl2,
                                            bnlg, bnlb, bnlrm, bnlrv, out);
}